// Round 1
// baseline (172.990 us; speedup 1.0000x reference)
//
#include <hip/hip_runtime.h>
#include <hip/hip_bf16.h>
#include <math.h>

#define H 128
#define R 8
#define NB 2
#define TT 64
#define THREE_H 384
#define TWO_H 256

typedef short short8 __attribute__((ext_vector_type(8)));
typedef __bf16 bf16x8_t __attribute__((ext_vector_type(8)));
typedef float f32x4 __attribute__((ext_vector_type(4)));

__device__ inline void split_bf(float f, unsigned short& hi, unsigned short& lo) {
    unsigned u = __builtin_bit_cast(unsigned, f);
    hi = (unsigned short)(u >> 16);
    float fhi = __builtin_bit_cast(float, u & 0xffff0000u);
    float d = f - fhi;
    lo = (unsigned short)(__builtin_bit_cast(unsigned, d) >> 16);
}

__device__ inline f32x4 mfma_bf16(short8 a, short8 b, f32x4 c) {
    return __builtin_amdgcn_mfma_f32_16x16x32_bf16(
        __builtin_bit_cast(bf16x8_t, a), __builtin_bit_cast(bf16x8_t, b), c, 0, 0, 0);
}

// ---------------- zero scratch ----------------
__global__ void k_zero(float* p, int n) {
    int i = blockIdx.x * 256 + threadIdx.x;
    if (i < n) p[i] = 0.f;
}

// ---------------- edge gather-sum: S[r][b][c], cnt[r] ----------------
__global__ void k_edges(const float* __restrict__ nodes, const int* __restrict__ src,
                        const int* __restrict__ rel, const int* __restrict__ dst,
                        float* __restrict__ Sg, float* __restrict__ cntg, int E, int epb) {
    __shared__ float S[R * 512];
    __shared__ float cnt[R];
    int t = threadIdx.x;
    for (int i = t; i < R * 512; i += 256) S[i] = 0.f;
    if (t < R) cnt[t] = 0.f;
    __syncthreads();

    int e0 = blockIdx.x * epb;
    int e1 = min(E, e0 + epb);
    int tS = ((t >> 7) << 8) + (t & 127);  // b*256 + h

    if (e0 < e1) {
        int r = rel[e0];
        float vs = nodes[src[e0] * 256 + t];
        float vd = nodes[dst[e0] * 256 + t];
        for (int e = e0; e < e1; ++e) {
            int rn = 0; float vsn = 0.f, vdn = 0.f;
            if (e + 1 < e1) {
                rn = rel[e + 1];
                vsn = nodes[src[e + 1] * 256 + t];
                vdn = nodes[dst[e + 1] * 256 + t];
            }
            S[r * 512 + tS] += vs;
            S[r * 512 + tS + 128] += vd;
            if (t == 0) cnt[r] += 1.f;
            vs = vsn; vd = vdn; r = rn;
        }
    }
    __syncthreads();
    for (int i = t; i < R * 512; i += 256) atomicAdd(&Sg[i], S[i]);
    if (t < R) atomicAdd(&cntg[t], cnt[t]);
}

// ---------------- gx = x @ Wih^T + bih : [T][B][3H] ----------------
__global__ void k_gx(const float* __restrict__ x, const float* __restrict__ Wih,
                     const float* __restrict__ bih, float* __restrict__ gx) {
    int tt = blockIdx.x >> 1, b = blockIdx.x & 1;
    __shared__ float xs[H];
    int t = threadIdx.x;  // 0..383
    if (t < H) xs[t] = x[(b * TT + tt) * H + t];
    __syncthreads();
    const float4* wp = (const float4*)(Wih + t * H);
    float acc = 0.f;
#pragma unroll
    for (int i = 0; i < 32; ++i) {
        float4 w = wp[i];
        acc += w.x * xs[4 * i] + w.y * xs[4 * i + 1] + w.z * xs[4 * i + 2] + w.w * xs[4 * i + 3];
    }
    gx[(tt * 2 + b) * THREE_H + t] = acc + bih[t];
}

// ---------------- combine: gs[b][h] = (sum_r S_r @ W_r + cnt_r*b_r)/E ----------------
__global__ void k_combine(const float* __restrict__ Sg, const float* __restrict__ cntg,
                          const float* __restrict__ relW, const float* __restrict__ relb,
                          float* __restrict__ gs, float invE) {
    int r = blockIdx.x;
    int t = threadIdx.x;  // 0..255
    __shared__ float Sl[512];
    Sl[t] = Sg[r * 512 + t];
    Sl[t + 256] = Sg[r * 512 + t + 256];
    __syncthreads();
    int b = t >> 7, h = t & 127;
    const float* W = relW + r * TWO_H * H;
    float acc = 0.f;
#pragma unroll 8
    for (int c = 0; c < TWO_H; ++c) acc += Sl[b * 256 + c] * W[c * H + h];
    acc += cntg[r] * relb[r * H + h];
    atomicAdd(&gs[t], acc * invE);
}

// ---------------- GRU (64 sequential steps) + MLP tail, single block ----------------
__launch_bounds__(512, 2)
__global__ void k_gru(const float* __restrict__ gx, const float* __restrict__ Whh,
                      const float* __restrict__ bhh, const float* __restrict__ gs,
                      const float* __restrict__ W1, const float* __restrict__ b1,
                      const float* __restrict__ lng, const float* __restrict__ lnb,
                      const float* __restrict__ W2, const float* __restrict__ b2,
                      float* __restrict__ out) {
    __shared__ float hf[NB][H];
    __shared__ unsigned short h_hi[3][H];
    __shared__ unsigned short h_lo[3][H];
    __shared__ float gh[NB][THREE_H];
    __shared__ float gl[NB][H];
    __shared__ float yl[NB][TWO_H];
    __shared__ float red[16];

    int t = threadIdx.x;
    int w = t >> 6;
    int l = t & 63;

    if (t < 256) hf[t >> 7][t & 127] = 0.f;
    if (t < 3 * H) { ((unsigned short*)h_hi)[t] = 0; ((unsigned short*)h_lo)[t] = 0; }

    // preload Whh^T fragments (B operand): wave w owns n-tiles w*3..w*3+2
    short8 Bhi[3][4], Blo[3][4];
#pragma unroll
    for (int ni = 0; ni < 3; ++ni) {
        int nt = w * 3 + ni;
        int row = nt * 16 + (l & 15);
#pragma unroll
        for (int kt = 0; kt < 4; ++kt) {
            int kb = kt * 32 + (l >> 4) * 8;
            const float4* wp = (const float4*)(Whh + row * H + kb);
            float4 w0 = wp[0], w1 = wp[1];
            float ww[8] = {w0.x, w0.y, w0.z, w0.w, w1.x, w1.y, w1.z, w1.w};
            short8 hi8, lo8;
#pragma unroll
            for (int e = 0; e < 8; ++e) {
                unsigned short hh, ll2;
                split_bf(ww[e], hh, ll2);
                hi8[e] = (short)hh;
                lo8[e] = (short)ll2;
            }
            Bhi[ni][kt] = hi8;
            Blo[ni][kt] = lo8;
        }
    }
    __syncthreads();

    int ab = l & 15;
    int rr = ab < 2 ? ab : 2;  // rows >=2 read the always-zero row (broadcast)
    int g = l >> 4;

    for (int step = 0; step < TT; ++step) {
        // A fragments (h, hi/lo) straight from LDS
        short8 Ahi[4], Alo[4];
#pragma unroll
        for (int kt = 0; kt < 4; ++kt) {
            int kb = kt * 32 + g * 8;
            Ahi[kt] = *(const short8*)&h_hi[rr][kb];
            Alo[kt] = *(const short8*)&h_lo[rr][kb];
        }
#pragma unroll
        for (int ni = 0; ni < 3; ++ni) {
            f32x4 acc = {0.f, 0.f, 0.f, 0.f};
#pragma unroll
            for (int kt = 0; kt < 4; ++kt) {
                acc = mfma_bf16(Ahi[kt], Bhi[ni][kt], acc);
                acc = mfma_bf16(Ahi[kt], Blo[ni][kt], acc);
                acc = mfma_bf16(Alo[kt], Bhi[ni][kt], acc);
            }
            int nt = w * 3 + ni;
            if (l < 16) {
                gh[0][nt * 16 + l] = acc[0];
                gh[1][nt * 16 + l] = acc[1];
            }
        }
        __syncthreads();
        if (t < 256) {
            int b = t >> 7, j = t & 127;
            const float* gxp = gx + (step * 2 + b) * THREE_H;
            float xr = gxp[j], xz = gxp[j + 128], xn = gxp[j + 256];
            float hr = gh[b][j] + bhh[j];
            float hz = gh[b][j + 128] + bhh[j + 128];
            float hn = gh[b][j + 256] + bhh[j + 256];
            float rg = 1.f / (1.f + __expf(-(xr + hr)));
            float zg = 1.f / (1.f + __expf(-(xz + hz)));
            float nn = xn + rg * hn;
            float th = 2.f / (1.f + __expf(-2.f * nn)) - 1.f;
            float hnew = (1.f - zg) * th + zg * hf[b][j];
            hf[b][j] = hnew;
            unsigned short hh, ll2;
            split_bf(hnew, hh, ll2);
            h_hi[b][j] = hh;
            h_lo[b][j] = ll2;
        }
        __syncthreads();
    }

    // ---- tail: g = gs + h ----
    if (t < 256) gl[t >> 7][t & 127] = gs[t] + hf[t >> 7][t & 127];
    __syncthreads();

    // h1[b][o] for o in [0,256): threads 0..255 compute both batches
    float h1_0 = 0.f, h1_1 = 0.f;
    if (t < 256) {
        int o = t;
        h1_0 = b1[o]; h1_1 = b1[o];
        for (int i = 0; i < H; ++i) {
            float wv = W1[i * TWO_H + o];
            h1_0 += gl[0][i] * wv;
            h1_1 += gl[1][i] * wv;
        }
    }
    // LN reductions over o (threads 0..255 hold one o each)
    float s10 = h1_0, s20 = h1_0 * h1_0, s11 = h1_1, s21 = h1_1 * h1_1;
    if (t >= 256) { s10 = s20 = s11 = s21 = 0.f; }
#pragma unroll
    for (int off = 32; off; off >>= 1) {
        s10 += __shfl_xor(s10, off);
        s20 += __shfl_xor(s20, off);
        s11 += __shfl_xor(s11, off);
        s21 += __shfl_xor(s21, off);
    }
    if (l == 0 && w < 4) {
        red[w * 4 + 0] = s10; red[w * 4 + 1] = s20;
        red[w * 4 + 2] = s11; red[w * 4 + 3] = s21;
    }
    __syncthreads();
    if (t < 256) {
        float S10 = red[0] + red[4] + red[8] + red[12];
        float S20 = red[1] + red[5] + red[9] + red[13];
        float S11 = red[2] + red[6] + red[10] + red[14];
        float S21 = red[3] + red[7] + red[11] + red[15];
        int o = t;
        float mu0 = S10 / 256.f, mu1 = S11 / 256.f;
        float v0 = S20 / 256.f - mu0 * mu0, v1 = S21 / 256.f - mu1 * mu1;
        float is0 = rsqrtf(v0 + 1e-5f), is1 = rsqrtf(v1 + 1e-5f);
        float y0 = (h1_0 - mu0) * is0 * lng[o] + lnb[o];
        float y1 = (h1_1 - mu1) * is1 * lng[o] + lnb[o];
        yl[0][o] = fmaxf(y0, 0.f);
        yl[1][o] = fmaxf(y1, 0.f);
    }
    __syncthreads();
    if (t < H) {
        int oo = t;
        float a0 = b2[oo], a1 = b2[oo];
        for (int i = 0; i < TWO_H; ++i) {
            float wv = W2[i * H + oo];
            a0 += yl[0][i] * wv;
            a1 += yl[1][i] * wv;
        }
        out[oo] = a0;
        out[H + oo] = a1;
    }
}

extern "C" void kernel_launch(void* const* d_in, const int* in_sizes, int n_in,
                              void* d_out, int out_size, void* d_ws, size_t ws_size,
                              hipStream_t stream) {
    const float* nodes = (const float*)d_in[0];
    const float* temporal = (const float*)d_in[1];
    const float* relW = (const float*)d_in[2];
    const float* relb = (const float*)d_in[3];
    const float* gru_Wih = (const float*)d_in[4];
    const float* gru_Whh = (const float*)d_in[5];
    const float* gru_bih = (const float*)d_in[6];
    const float* gru_bhh = (const float*)d_in[7];
    const float* mlp_W1 = (const float*)d_in[8];
    const float* mlp_b1 = (const float*)d_in[9];
    const float* ln_g = (const float*)d_in[10];
    const float* ln_b = (const float*)d_in[11];
    const float* mlp_W2 = (const float*)d_in[12];
    const float* mlp_b2 = (const float*)d_in[13];
    const int* src = (const int*)d_in[14];
    const int* rel = (const int*)d_in[15];
    const int* dst = (const int*)d_in[16];
    float* out = (float*)d_out;

    int E = in_sizes[14];

    float* ws = (float*)d_ws;
    float* S = ws;             // 4096
    float* cnt = ws + 4096;    // 8
    float* gs = ws + 4104;     // 256
    float* gx = ws + 4608;     // 49152

    k_zero<<<18, 256, 0, stream>>>(ws, 4360);

    const int NBLK = 1024;
    int epb = (E + NBLK - 1) / NBLK;
    k_edges<<<NBLK, 256, 0, stream>>>(nodes, src, rel, dst, S, cnt, E, epb);

    k_gx<<<128, 384, 0, stream>>>(temporal, gru_Wih, gru_bih, gx);

    k_combine<<<8, 256, 0, stream>>>(S, cnt, relW, relb, gs, 1.f / (float)E);

    k_gru<<<1, 512, 0, stream>>>(gx, gru_Whh, gru_bhh, gs, mlp_W1, mlp_b1,
                                 ln_g, ln_b, mlp_W2, mlp_b2, out);
}